// Round 1
// baseline (1167.218 us; speedup 1.0000x reference)
//
#include <hip/hip_runtime.h>

#define T_TOK 4096
#define HID   2048
#define INTER 2048
#define NEXP  8
#define TK    8192   // T_TOK * TOPK
#define MAXMB 40     // 256-row m-tiles: worst case 39; padded to 8*5 for XCD swizzle
#define NT    32     // 2048 / 64 K-steps

typedef __bf16 bf16x8 __attribute__((ext_vector_type(8)));
typedef float  f32x4  __attribute__((ext_vector_type(4)));

__device__ __forceinline__ unsigned short f2bf(float f) {
    unsigned u = __builtin_bit_cast(unsigned, f);
    u += 0x7FFFu + ((u >> 16) & 1u);   // RNE; inputs are finite
    return (unsigned short)(u >> 16);
}

// async global -> LDS, 16B per lane; LDS dest is wave-uniform base + lane*16
__device__ __forceinline__ void gload_lds16(const unsigned short* g, unsigned short* l) {
    __builtin_amdgcn_global_load_lds(
        (const __attribute__((address_space(1))) unsigned int*)g,
        (__attribute__((address_space(3))) unsigned int*)l,
        16, 0, 0);
}

// ---------------- fp32 -> bf16 bulk convert (x and weights) ----------------
__global__ void cvt_kernel(const float4* __restrict__ src,
                           ushort4* __restrict__ dst, int n4) {
    int i = blockIdx.x * 256 + threadIdx.x;
    if (i < n4) {
        float4 v = src[i];
        ushort4 o;
        o.x = f2bf(v.x); o.y = f2bf(v.y); o.z = f2bf(v.z); o.w = f2bf(v.w);
        dst[i] = o;
    }
}

// ------- routing: histogram + prefix + scatter + compact block table -------
__global__ void route_kernel(const int* __restrict__ topk,
                             int* __restrict__ offsets,
                             int* __restrict__ sorted,
                             int* __restrict__ btab,
                             int* __restrict__ nbt) {
    __shared__ int cnt[NEXP];
    __shared__ int pos[NEXP];
    int tid = threadIdx.x;
    if (tid < NEXP) cnt[tid] = 0;
    __syncthreads();
    for (int i = tid; i < TK; i += 256) atomicAdd(&cnt[topk[i]], 1);
    __syncthreads();
    if (tid == 0) {
        int s = 0;
        for (int e = 0; e < NEXP; e++) { offsets[e] = s; pos[e] = s; s += cnt[e]; }
        offsets[NEXP] = s;
        int nb = 0;
        for (int e = 0; e < NEXP; e++) {
            int nmb = (cnt[e] + 255) >> 8;           // 256-row m-tiles now
            for (int m = 0; m < nmb; m++) btab[nb++] = (e << 16) | m;
        }
        nbt[0] = nb;   // <= 39
    }
    __syncthreads();
    for (int i = tid; i < TK; i += 256) {
        int e = topk[i];
        int p = atomicAdd(&pos[e], 1);
        sorted[p] = i;
    }
}

// ---- grouped GEMM, 256x256 fragment tile, dbuf LDS, 2-phase pipeline ------
// LDS tile layout (A and B, 256 rows x 64 cols bf16): 16B chunk at byte addr
//   (k8*256 + row)*16, k8 = k/8 in [0,8).  HW lane-sequential global_load_lds
//   write order == MFMA fragment read order (same invariant as prior kernel).
// 512 threads = 8 waves as 2(M) x 4(N); per-wave output 128 x 64 fragment
// rows/cols, acc[8][4] f32x4 (128 VGPR).
// MODE 0 (gate_up + fused SwiGLU): out tile = 256 tokens x 128 cols.
//   B tile rows interleave gate/up at 16-granularity: B-row r = 32q+s,
//   s<16 -> gate col n0+16q+s, s>=16 -> up col n0+16q+(s-16).  Then for each
//   thread acc[mt][2p] = gate, acc[mt][2p+1] = up of the SAME output column.
// MODE 1 (down): out tile = 256 rows x 256 cols; atomicAdd epilogue.
// K-loop: issue next tile's global_load_lds BEFORE computing current buffer;
// single __syncthreads per K-step (= vmcnt(0)+lgkmcnt(0)+barrier) drains the
// prefetch after MFMA, hiding the staging latency under compute.
template <int MODE>
__global__ __launch_bounds__(512, 2)
void moe_gemm(const unsigned short* __restrict__ A_src,
              const unsigned short* __restrict__ W,   // bf16 weights [e][NWROW][2048]
              const int* __restrict__ offsets,
              const int* __restrict__ sorted,
              const float* __restrict__ wts,
              const int* __restrict__ btab,
              const int* __restrict__ nbt,
              unsigned short* __restrict__ act,
              float* __restrict__ out) {
    constexpr int KD    = 2048;
    constexpr int NWROW = (MODE == 0) ? 4096 : 2048;

    // bijective XCD swizzle: gridDim.x = 40 = 8*5; ids == c (mod 8) share an
    // XCD and map to 5 consecutive m-tiles of the same n-panel -> L2 reuse.
    const int bx = (blockIdx.x & 7) * (MAXMB / 8) + (blockIdx.x >> 3);
    if (bx >= nbt[0]) return;
    const int ent = btab[bx];
    const int e   = ent >> 16;
    const int off = offsets[e];
    const int cnt = offsets[e + 1] - off;
    const int m0  = (ent & 0xffff) * 256;
    const int n0  = blockIdx.y * ((MODE == 0) ? 128 : 256);
    const unsigned short* Wb = W + (size_t)e * NWROW * KD;

    __shared__ unsigned short Asm[2][16384];   // 2 x 32 KB
    __shared__ unsigned short Bsm[2][16384];   // 2 x 32 KB
    __shared__ int rowid[256];

    const int tid = threadIdx.x;
    if (tid < 256) {
        int gm = m0 + tid;
        if (MODE == 0) rowid[tid] = (gm < cnt) ? (sorted[off + gm] >> 1) : 0;
        else           rowid[tid] = off + ((gm < cnt) ? gm : (cnt - 1));
    }
    __syncthreads();

    const int wave = tid >> 6, lane = tid & 63;
    const int quad = lane >> 4, lrow = lane & 15;
    const int wm = wave >> 2, wn = wave & 3;

    // ---- staging descriptors (hoisted; only +k0 changes per iter) ----
    // wave w stages k8 = w; issue c covers tile rows c*64 + lane.
    const unsigned short* asrc[4];
    const unsigned short* bsrc[4];
    int dstoff[4];
#pragma unroll
    for (int c = 0; c < 4; c++) {
        int r = c * 64 + lane;
        asrc[c] = A_src + (size_t)rowid[r] * KD + wave * 8;
        int wr;
        if (MODE == 0) wr = n0 + (r >> 5) * 16 + (r & 15) + ((r >> 4) & 1) * 2048;
        else           wr = n0 + r;
        bsrc[c] = Wb + (size_t)wr * KD + wave * 8;
        dstoff[c] = (wave * 256 + c * 64) * 8;   // wave-uniform chunk base
    }

    const int ardoff = (quad * 256 + wm * 128 + lrow) * 8;
    const int brdoff = (quad * 256 + wn * 64 + lrow) * 8;

    f32x4 acc[8][4];
#pragma unroll
    for (int i = 0; i < 8; i++)
#pragma unroll
        for (int j = 0; j < 4; j++) acc[i][j] = (f32x4){0.f, 0.f, 0.f, 0.f};

    auto STAGE = [&](int buf, int k0) {
#pragma unroll
        for (int c = 0; c < 4; c++) {
            gload_lds16(asrc[c] + k0, &Asm[buf][dstoff[c]]);
            gload_lds16(bsrc[c] + k0, &Bsm[buf][dstoff[c]]);
        }
    };

    STAGE(0, 0);
    __syncthreads();   // vmcnt(0) + barrier: buf0 resident

    int cur = 0;
    for (int t = 0; t < NT; ++t) {
        if (t + 1 < NT) STAGE(cur ^ 1, (t + 1) * 64);   // prefetch next tile

        const unsigned short* a0 = &Asm[cur][ardoff];
        const unsigned short* b0 = &Bsm[cur][brdoff];
#pragma unroll
        for (int ks = 0; ks < 2; ++ks) {
            bf16x8 af[8], bfr[4];
#pragma unroll
            for (int mt = 0; mt < 8; mt++)
                af[mt] = *(const bf16x8*)(a0 + ks * 8192 + mt * 128);
#pragma unroll
            for (int nt = 0; nt < 4; nt++)
                bfr[nt] = *(const bf16x8*)(b0 + ks * 8192 + nt * 128);
#pragma unroll
            for (int mt = 0; mt < 8; mt++)
#pragma unroll
                for (int nt = 0; nt < 4; nt++)
                    acc[mt][nt] = __builtin_amdgcn_mfma_f32_16x16x32_bf16(
                        af[mt], bfr[nt], acc[mt][nt], 0, 0, 0);
        }
        __syncthreads();   // drains prefetch vmcnt + barrier; buf[cur^1] ready
        cur ^= 1;
    }

    // epilogue: C/D layout col = lane&15 (lrow), row = quad*4 + reg
    if (MODE == 0) {
#pragma unroll
        for (int mt = 0; mt < 8; mt++) {
#pragma unroll
            for (int r = 0; r < 4; r++) {
                int gm = m0 + wm * 128 + mt * 16 + quad * 4 + r;
                if (gm < cnt) {
                    unsigned short* arow = act + (size_t)(off + gm) * 2048;
#pragma unroll
                    for (int p = 0; p < 2; p++) {
                        int col = n0 + wn * 32 + p * 16 + lrow;
                        float g = acc[mt][2 * p][r];
                        float u = acc[mt][2 * p + 1][r];
                        float s = g / (1.f + __expf(-g));
                        arow[col] = f2bf(s * u);
                    }
                }
            }
        }
    } else {
#pragma unroll
        for (int mt = 0; mt < 8; mt++) {
#pragma unroll
            for (int r = 0; r < 4; r++) {
                int gm = m0 + wm * 128 + mt * 16 + quad * 4 + r;
                if (gm < cnt) {
                    int idx = sorted[off + gm];
                    float w = wts[idx];
                    float* orow = out + (size_t)(idx >> 1) * HID;
#pragma unroll
                    for (int nt = 0; nt < 4; nt++) {
                        int n = n0 + wn * 64 + nt * 16 + lrow;
                        atomicAdd(orow + n, w * acc[mt][nt][r]);
                    }
                }
            }
        }
    }
}

extern "C" void kernel_launch(void* const* d_in, const int* in_sizes, int n_in,
                              void* d_out, int out_size, void* d_ws, size_t ws_size,
                              hipStream_t stream) {
    const float* x    = (const float*)d_in[0];   // [4096, 2048] fp32
    const int*   topk = (const int*)d_in[1];     // [4096, 2] int32
    const float* wts  = (const float*)d_in[2];   // [4096, 2] fp32
    const float* Wgu  = (const float*)d_in[3];   // [8, 4096, 2048] fp32
    const float* Wd   = (const float*)d_in[4];   // [8, 2048, 2048] fp32
    float* out = (float*)d_out;

    // ws layout (Wd_bf aliases Wgu_bf: converted after GEMM1, stream-serial):
    //   [0, 64K)            tables
    //   [64K, +134.2M)      Wgu_bf  (later overwritten by Wd_bf, 67.1M)
    //   [+, +16.8M)         x_bf
    //   [+, +33.6M)         act     -> total ~184.7 MB
    char* ws = (char*)d_ws;
    int* offsets = (int*)ws;
    int* sorted  = offsets + 16;
    int* btab    = offsets + 8208;
    int* nbt     = offsets + 8336;
    unsigned short* Wgu_bf = (unsigned short*)(ws + 65536);
    unsigned short* Wd_bf  = Wgu_bf;   // alias, written after GEMM1
    unsigned short* x_bf   = (unsigned short*)(ws + 65536 + (size_t)NEXP * 2 * INTER * HID * 2);
    unsigned short* act    = x_bf + (size_t)T_TOK * HID;

    hipMemsetAsync(d_out, 0, (size_t)out_size * sizeof(float), stream);

    cvt_kernel<<<(T_TOK * HID / 4) / 256, 256, 0, stream>>>(
        (const float4*)x, (ushort4*)x_bf, T_TOK * HID / 4);
    cvt_kernel<<<(NEXP * 2 * INTER * HID / 4) / 256, 256, 0, stream>>>(
        (const float4*)Wgu, (ushort4*)Wgu_bf, NEXP * 2 * INTER * HID / 4);

    route_kernel<<<1, 256, 0, stream>>>(topk, offsets, sorted, btab, nbt);

    // GEMM1 + fused SwiGLU: act = silu(x@gate^T) * (x@up^T), bf16 [TK, 2048]
    moe_gemm<0><<<dim3(MAXMB, 16), 512, 0, stream>>>(
        x_bf, Wgu_bf, offsets, sorted, wts, btab, nbt, act, nullptr);

    cvt_kernel<<<(NEXP * HID * INTER / 4) / 256, 256, 0, stream>>>(
        (const float4*)Wd, (ushort4*)Wd_bf, NEXP * HID * INTER / 4);

    // GEMM2: out[token] += w * (act @ down[e]^T)
    moe_gemm<1><<<dim3(MAXMB, 8), 512, 0, stream>>>(
        act, Wd_bf, offsets, sorted, wts, btab, nbt, nullptr, out);
}

// Round 3
// 935.570 us; speedup vs baseline: 1.2476x; 1.2476x over previous
//
#include <hip/hip_runtime.h>

#define T_TOK 4096
#define HID   2048
#define INTER 2048
#define NEXP  8
#define TK    8192   // T_TOK * TOPK
#define MAXMB 40     // 256-row m-tiles: worst case 39; padded to 8*5 for XCD swizzle
#define NT    32     // 2048 / 64 K-steps

typedef __bf16 bf16x8 __attribute__((ext_vector_type(8)));
typedef float  f32x4  __attribute__((ext_vector_type(4)));

__device__ __forceinline__ unsigned short f2bf(float f) {
    unsigned u = __builtin_bit_cast(unsigned, f);
    u += 0x7FFFu + ((u >> 16) & 1u);   // RNE; inputs are finite
    return (unsigned short)(u >> 16);
}

// async global -> LDS, 16B per lane; LDS dest is wave-uniform base + lane*16
__device__ __forceinline__ void gload_lds16(const unsigned short* g, unsigned short* l) {
    __builtin_amdgcn_global_load_lds(
        (const __attribute__((address_space(1))) unsigned int*)g,
        (__attribute__((address_space(3))) unsigned int*)l,
        16, 0, 0);
}

// ---------------- fp32 -> bf16 bulk convert (x and weights) ----------------
__global__ void cvt_kernel(const float4* __restrict__ src,
                           ushort4* __restrict__ dst, int n4) {
    int i = blockIdx.x * 256 + threadIdx.x;
    if (i < n4) {
        float4 v = src[i];
        ushort4 o;
        o.x = f2bf(v.x); o.y = f2bf(v.y); o.z = f2bf(v.z); o.w = f2bf(v.w);
        dst[i] = o;
    }
}

// ------- routing: histogram + prefix + scatter + compact block table -------
__global__ void route_kernel(const int* __restrict__ topk,
                             int* __restrict__ offsets,
                             int* __restrict__ sorted,
                             int* __restrict__ btab,
                             int* __restrict__ nbt) {
    __shared__ int cnt[NEXP];
    __shared__ int pos[NEXP];
    int tid = threadIdx.x;
    if (tid < NEXP) cnt[tid] = 0;
    __syncthreads();
    for (int i = tid; i < TK; i += 256) atomicAdd(&cnt[topk[i]], 1);
    __syncthreads();
    if (tid == 0) {
        int s = 0;
        for (int e = 0; e < NEXP; e++) { offsets[e] = s; pos[e] = s; s += cnt[e]; }
        offsets[NEXP] = s;
        int nb = 0;
        for (int e = 0; e < NEXP; e++) {
            int nmb = (cnt[e] + 255) >> 8;           // 256-row m-tiles
            for (int m = 0; m < nmb; m++) btab[nb++] = (e << 16) | m;
        }
        nbt[0] = nb;   // <= 39
    }
    __syncthreads();
    for (int i = tid; i < TK; i += 256) {
        int e = topk[i];
        int p = atomicAdd(&pos[e], 1);
        sorted[p] = i;
    }
}

// ---- grouped GEMM, 256x256 fragment tile, dbuf LDS, 2-phase pipeline ------
// LDS image: row-major [256 rows][64 k-elems] bf16 (128B rows), with T2 XOR
// swizzle on the 16B chunk index: logical (row, k8) lives at chunk
//   row*8 + (k8 ^ (row&7)).
// Staging: each global_load_lds covers 8 rows x 128B (lanes 0-7 = one row's
// full BK slice) -> 16 cache lines per instr (vs 64 for the old 64-rows x 16B
// pattern; that request-scatter was the round-1 bottleneck: MfmaUtil pinned at
// 15.7% with HBM at 7%).  LDS dest stays linear (HW requirement); the swizzle
// is applied on the per-lane GLOBAL source chunk (k8src = (lane&7)^(lane>>3&7),
// rule: inverse-swizzle source + swizzled read).
// ds_read: chunk = row*8 + (k8 ^ (row&7)) -> 8 lanes per 16B slot spread over
// distinct processing groups (= conflict-free b128 baseline density).
// 512 threads = 8 waves as 2(M) x 4(N); per-wave output 128 x 64 fragment
// rows/cols, acc[8][4] f32x4.
// MODE 0 (gate_up + fused SwiGLU): B tile rows interleave gate/up at
// 16-granularity so acc[mt][2p]/acc[mt][2p+1] = gate/up of the same column.
// MODE 1 (down): 256x256 out tile; atomicAdd epilogue.
template <int MODE>
__global__ __launch_bounds__(512, 2)
void moe_gemm(const unsigned short* __restrict__ A_src,
              const unsigned short* __restrict__ W,   // bf16 weights [e][NWROW][2048]
              const int* __restrict__ offsets,
              const int* __restrict__ sorted,
              const float* __restrict__ wts,
              const int* __restrict__ btab,
              const int* __restrict__ nbt,
              unsigned short* __restrict__ act,
              float* __restrict__ out) {
    constexpr int KD    = 2048;
    constexpr int NWROW = (MODE == 0) ? 4096 : 2048;

    // bijective XCD swizzle: gridDim.x = 40 = 8*5; same-XCD blocks are 5
    // consecutive m-tiles of the same n-panel -> L2 reuse of the B panel.
    const int bx = (blockIdx.x & 7) * (MAXMB / 8) + (blockIdx.x >> 3);
    if (bx >= nbt[0]) return;
    const int ent = btab[bx];
    const int e   = ent >> 16;
    const int off = offsets[e];
    const int cnt = offsets[e + 1] - off;
    const int m0  = (ent & 0xffff) * 256;
    const int n0  = blockIdx.y * ((MODE == 0) ? 128 : 256);
    const unsigned short* Wb = W + (size_t)e * NWROW * KD;

    __shared__ unsigned short Asm[2][16384];   // 2 x 32 KB
    __shared__ unsigned short Bsm[2][16384];   // 2 x 32 KB
    __shared__ int rowid[256];

    const int tid = threadIdx.x;
    if (tid < 256) {
        int gm = m0 + tid;
        if (MODE == 0) rowid[tid] = (gm < cnt) ? (sorted[off + gm] >> 1) : 0;
        else           rowid[tid] = off + ((gm < cnt) ? gm : (cnt - 1));
    }
    __syncthreads();

    const int wave = tid >> 6, lane = tid & 63;
    const int quad = lane >> 4, lrow = lane & 15;
    const int wm = wave >> 2, wn = wave & 3;

    // ---- staging descriptors (hoisted; only +k0 changes per iter) ----
    // instr c: LDS rows [wave*32 + c*8, +8); lane covers row += lane>>3,
    // source 16B chunk k8src = (lane&7) ^ ((lane>>3)&7)  (T2 inverse swizzle).
    const int lrg = lane >> 3;          // row within 8-row group
    const int kx  = (lane & 7) ^ lrg;   // xor'd source chunk
    const unsigned short* asrc[4];
    const unsigned short* bsrc[4];
    int dstoff[4];
#pragma unroll
    for (int c = 0; c < 4; c++) {
        int r = wave * 32 + c * 8 + lrg;     // tile row 0..255
        asrc[c] = A_src + (size_t)rowid[r] * KD + kx * 8;
        int wr;
        if (MODE == 0) wr = n0 + (r >> 5) * 16 + (r & 15) + ((r >> 4) & 1) * 2048;
        else           wr = n0 + r;
        bsrc[c] = Wb + (size_t)wr * KD + kx * 8;
        dstoff[c] = (wave * 32 + c * 8) * 64;   // shorts; wave-uniform
    }

    // ---- ds_read bases: logical (row, k8) -> chunk row*8 + (k8 ^ (row&7));
    // row&7 == lrow&7 for all fragment rows (bases are multiples of 16).
    const int sw = lrow & 7;
    const int Ra = wm * 128 + lrow;
    const int Rb = wn * 64 + lrow;
    const int akoff[2] = { Ra * 64 + ((quad ^ sw) * 8),
                           Ra * 64 + (((quad + 4) ^ sw) * 8) };
    const int bkoff[2] = { Rb * 64 + ((quad ^ sw) * 8),
                           Rb * 64 + (((quad + 4) ^ sw) * 8) };

    f32x4 acc[8][4];
#pragma unroll
    for (int i = 0; i < 8; i++)
#pragma unroll
        for (int j = 0; j < 4; j++) acc[i][j] = (f32x4){0.f, 0.f, 0.f, 0.f};

    auto STAGE = [&](int buf, int k0) {
#pragma unroll
        for (int c = 0; c < 4; c++) {
            gload_lds16(asrc[c] + k0, &Asm[buf][dstoff[c]]);
            gload_lds16(bsrc[c] + k0, &Bsm[buf][dstoff[c]]);
        }
    };

    STAGE(0, 0);
    __syncthreads();   // vmcnt(0) + barrier: buf0 resident

    int cur = 0;
    for (int t = 0; t < NT; ++t) {
        if (t + 1 < NT) STAGE(cur ^ 1, (t + 1) * 64);   // prefetch next tile

        const unsigned short* A0 = Asm[cur];
        const unsigned short* B0 = Bsm[cur];
#pragma unroll
        for (int ks = 0; ks < 2; ++ks) {
            bf16x8 af[8], bfr[4];
#pragma unroll
            for (int mt = 0; mt < 8; mt++)
                af[mt] = *(const bf16x8*)(A0 + akoff[ks] + mt * 1024);
#pragma unroll
            for (int nt = 0; nt < 4; nt++)
                bfr[nt] = *(const bf16x8*)(B0 + bkoff[ks] + nt * 1024);
#pragma unroll
            for (int mt = 0; mt < 8; mt++)
#pragma unroll
                for (int nt = 0; nt < 4; nt++)
                    acc[mt][nt] = __builtin_amdgcn_mfma_f32_16x16x32_bf16(
                        af[mt], bfr[nt], acc[mt][nt], 0, 0, 0);
        }
        __syncthreads();   // drains prefetch vmcnt + barrier; buf[cur^1] ready
        cur ^= 1;
    }

    // epilogue: C/D layout col = lane&15 (lrow), row = quad*4 + reg
    if (MODE == 0) {
#pragma unroll
        for (int mt = 0; mt < 8; mt++) {
#pragma unroll
            for (int r = 0; r < 4; r++) {
                int gm = m0 + wm * 128 + mt * 16 + quad * 4 + r;
                if (gm < cnt) {
                    unsigned short* arow = act + (size_t)(off + gm) * 2048;
#pragma unroll
                    for (int p = 0; p < 2; p++) {
                        int col = n0 + wn * 32 + p * 16 + lrow;
                        float g = acc[mt][2 * p][r];
                        float u = acc[mt][2 * p + 1][r];
                        float s = g / (1.f + __expf(-g));
                        arow[col] = f2bf(s * u);
                    }
                }
            }
        }
    } else {
#pragma unroll
        for (int mt = 0; mt < 8; mt++) {
#pragma unroll
            for (int r = 0; r < 4; r++) {
                int gm = m0 + wm * 128 + mt * 16 + quad * 4 + r;
                if (gm < cnt) {
                    int idx = sorted[off + gm];
                    float w = wts[idx];
                    float* orow = out + (size_t)(idx >> 1) * HID;
#pragma unroll
                    for (int nt = 0; nt < 4; nt++) {
                        int n = n0 + wn * 64 + nt * 16 + lrow;
                        atomicAdd(orow + n, w * acc[mt][nt][r]);
                    }
                }
            }
        }
    }
}

extern "C" void kernel_launch(void* const* d_in, const int* in_sizes, int n_in,
                              void* d_out, int out_size, void* d_ws, size_t ws_size,
                              hipStream_t stream) {
    const float* x    = (const float*)d_in[0];   // [4096, 2048] fp32
    const int*   topk = (const int*)d_in[1];     // [4096, 2] int32
    const float* wts  = (const float*)d_in[2];   // [4096, 2] fp32
    const float* Wgu  = (const float*)d_in[3];   // [8, 4096, 2048] fp32
    const float* Wd   = (const float*)d_in[4];   // [8, 2048, 2048] fp32
    float* out = (float*)d_out;

    // ws layout (Wd_bf aliases Wgu_bf: converted after GEMM1, stream-serial):
    //   [0, 64K)            tables
    //   [64K, +134.2M)      Wgu_bf  (later overwritten by Wd_bf, 67.1M)
    //   [+, +16.8M)         x_bf
    //   [+, +33.6M)         act     -> total ~184.7 MB
    char* ws = (char*)d_ws;
    int* offsets = (int*)ws;
    int* sorted  = offsets + 16;
    int* btab    = offsets + 8208;
    int* nbt     = offsets + 8336;
    unsigned short* Wgu_bf = (unsigned short*)(ws + 65536);
    unsigned short* Wd_bf  = Wgu_bf;   // alias, written after GEMM1
    unsigned short* x_bf   = (unsigned short*)(ws + 65536 + (size_t)NEXP * 2 * INTER * HID * 2);
    unsigned short* act    = x_bf + (size_t)T_TOK * HID;

    hipMemsetAsync(d_out, 0, (size_t)out_size * sizeof(float), stream);

    cvt_kernel<<<(T_TOK * HID / 4) / 256, 256, 0, stream>>>(
        (const float4*)x, (ushort4*)x_bf, T_TOK * HID / 4);
    cvt_kernel<<<(NEXP * 2 * INTER * HID / 4) / 256, 256, 0, stream>>>(
        (const float4*)Wgu, (ushort4*)Wgu_bf, NEXP * 2 * INTER * HID / 4);

    route_kernel<<<1, 256, 0, stream>>>(topk, offsets, sorted, btab, nbt);

    // GEMM1 + fused SwiGLU: act = silu(x@gate^T) * (x@up^T), bf16 [TK, 2048]
    moe_gemm<0><<<dim3(MAXMB, 16), 512, 0, stream>>>(
        x_bf, Wgu_bf, offsets, sorted, wts, btab, nbt, act, nullptr);

    cvt_kernel<<<(NEXP * HID * INTER / 4) / 256, 256, 0, stream>>>(
        (const float4*)Wd, (ushort4*)Wd_bf, NEXP * HID * INTER / 4);

    // GEMM2: out[token] += w * (act @ down[e]^T)
    moe_gemm<1><<<dim3(MAXMB, 8), 512, 0, stream>>>(
        act, Wd_bf, offsets, sorted, wts, btab, nbt, nullptr, out);
}